// Round 1
// baseline (941.065 us; speedup 1.0000x reference)
//
#include <hip/hip_runtime.h>
#include <hip/hip_fp16.h>

#define GSZ 512
#define CCH 48
#define GG (GSZ*GSZ)

// ---------------- repack planes [C,H,W] fp32 -> [H*W, C] fp16 ----------------
__global__ __launch_bounds__(256) void transpose_plane(const float* __restrict__ in,
                                                       __half* __restrict__ out) {
    __shared__ float tile[CCH][65];   // +1 pad: bank = (c+p)%32 -> <=2-way (free)
    const int t = threadIdx.x;
    const int pos0 = blockIdx.x * 64;            // 64 (y,x) positions per block
    #pragma unroll
    for (int k = 0; k < 12; ++k) {
        int e = k * 256 + t;                     // 0..3071
        int c = e >> 6;
        int p = e & 63;
        tile[c][p] = in[c * GG + pos0 + p];      // coalesced per wave
    }
    __syncthreads();
    #pragma unroll
    for (int k = 0; k < 6; ++k) {
        int e = (k * 256 + t) * 2;               // even, pairs share a position
        int p = e / 48;
        int c = e - p * 48;
        __half2 h;
        h.x = __float2half(tile[c][p]);
        h.y = __float2half(tile[c + 1][p]);
        *((__half2*)(out + (size_t)pos0 * CCH + e)) = h;  // coalesced 4B stores
    }
}

// ---------------- repack lines [C,G] fp32 -> [G, C] fp16 (tiny) ----------------
__global__ __launch_bounds__(256) void transpose_lines(
    const float* __restrict__ i0, const float* __restrict__ i1, const float* __restrict__ i2,
    __half* __restrict__ o0, __half* __restrict__ o1, __half* __restrict__ o2) {
    int idx = blockIdx.x * blockDim.x + threadIdx.x;
    const int total = CCH * GSZ;
    if (idx >= 3 * total) return;
    int w = idx / total;
    int r = idx - w * total;
    int c = r / GSZ;
    int p = r - c * GSZ;
    const float* in = (w == 0) ? i0 : (w == 1) ? i1 : i2;
    __half* out = (w == 0) ? o0 : (w == 1) ? o1 : o2;
    out[p * CCH + c] = __float2half(in[c * GSZ + p]);
}

union H8 { int4 v; __half h[8]; };

// ---------------- fused gather: bilinear plane * linear line ----------------
__global__ __launch_bounds__(256) void gather_fused(
    const float* __restrict__ xyz,
    const __half* __restrict__ p0, const __half* __restrict__ p1, const __half* __restrict__ p2,
    const __half* __restrict__ l0, const __half* __restrict__ l1, const __half* __restrict__ l2,
    float* __restrict__ out, int N) {
    int n = blockIdx.x * blockDim.x + threadIdx.x;
    if (n >= N) return;
    float x = xyz[3 * n + 0], y = xyz[3 * n + 1], z = xyz[3 * n + 2];

    // MAT_MODE = [(0,1),(0,2),(1,2)]  (gx -> W, gy -> H);  VEC_MODE = [2,1,0]
    float gx[3] = {x, x, y};
    float gy[3] = {y, z, z};
    float gz[3] = {z, y, x};

    int   po[3][4];
    int   lo[3][2];
    float wx[3], wy[3], wz[3];
    #pragma unroll
    for (int i = 0; i < 3; ++i) {
        float ix = (gx[i] + 1.0f) * 0.5f * (float)(GSZ - 1);
        float iy = (gy[i] + 1.0f) * 0.5f * (float)(GSZ - 1);
        float ix0f = fminf(fmaxf(floorf(ix), 0.0f), (float)(GSZ - 1));
        float iy0f = fminf(fmaxf(floorf(iy), 0.0f), (float)(GSZ - 1));
        int ix0 = (int)ix0f, iy0 = (int)iy0f;
        int ix1 = min(ix0 + 1, GSZ - 1);
        int iy1 = min(iy0 + 1, GSZ - 1);
        wx[i] = ix - ix0f;
        wy[i] = iy - iy0f;
        po[i][0] = (iy0 * GSZ + ix0) * CCH;
        po[i][1] = (iy0 * GSZ + ix1) * CCH;
        po[i][2] = (iy1 * GSZ + ix0) * CCH;
        po[i][3] = (iy1 * GSZ + ix1) * CCH;
        float iz = (gz[i] + 1.0f) * 0.5f * (float)(GSZ - 1);
        float iz0f = fminf(fmaxf(floorf(iz), 0.0f), (float)(GSZ - 1));
        int iz0 = (int)iz0f;
        int iz1 = min(iz0 + 1, GSZ - 1);
        wz[i] = iz - iz0f;
        lo[i][0] = iz0 * CCH;
        lo[i][1] = iz1 * CCH;
    }

    const size_t CN = (size_t)CCH * (size_t)N;
    #pragma unroll
    for (int i = 0; i < 3; ++i) {
        const __half* pp = (i == 0) ? p0 : (i == 1) ? p1 : p2;
        const __half* ll = (i == 0) ? l0 : (i == 1) ? l1 : l2;
        float* op = out + (size_t)i * CN + n;
        #pragma unroll
        for (int cc = 0; cc < CCH; cc += 8) {
            H8 a00, a01, a10, a11, b0, b1;
            a00.v = *(const int4*)(pp + po[i][0] + cc);
            a01.v = *(const int4*)(pp + po[i][1] + cc);
            a10.v = *(const int4*)(pp + po[i][2] + cc);
            a11.v = *(const int4*)(pp + po[i][3] + cc);
            b0.v  = *(const int4*)(ll + lo[i][0] + cc);
            b1.v  = *(const int4*)(ll + lo[i][1] + cc);
            #pragma unroll
            for (int j = 0; j < 8; ++j) {
                float v00 = __half2float(a00.h[j]);
                float v01 = __half2float(a01.h[j]);
                float v10 = __half2float(a10.h[j]);
                float v11 = __half2float(a11.h[j]);
                float top = fmaf(wx[i], v01 - v00, v00);
                float bot = fmaf(wx[i], v11 - v10, v10);
                float pc  = fmaf(wy[i], bot - top, top);
                float lv0 = __half2float(b0.h[j]);
                float lv1 = __half2float(b1.h[j]);
                float lc  = fmaf(wz[i], lv1 - lv0, lv0);
                op[(size_t)(cc + j) * N] = pc * lc;   // coalesced across lanes
            }
        }
    }
}

// ---------------- fallback: direct fp32 gather from original layout ----------------
__global__ __launch_bounds__(256) void gather_direct(
    const float* __restrict__ xyz,
    const float* __restrict__ p0, const float* __restrict__ p1, const float* __restrict__ p2,
    const float* __restrict__ l0, const float* __restrict__ l1, const float* __restrict__ l2,
    float* __restrict__ out, int N) {
    int n = blockIdx.x * blockDim.x + threadIdx.x;
    if (n >= N) return;
    float x = xyz[3 * n + 0], y = xyz[3 * n + 1], z = xyz[3 * n + 2];
    float gx[3] = {x, x, y};
    float gy[3] = {y, z, z};
    float gz[3] = {z, y, x};
    int q[3][4], lz[3][2];
    float wx[3], wy[3], wz[3];
    #pragma unroll
    for (int i = 0; i < 3; ++i) {
        float ix = (gx[i] + 1.0f) * 0.5f * (float)(GSZ - 1);
        float iy = (gy[i] + 1.0f) * 0.5f * (float)(GSZ - 1);
        float ix0f = fminf(fmaxf(floorf(ix), 0.0f), (float)(GSZ - 1));
        float iy0f = fminf(fmaxf(floorf(iy), 0.0f), (float)(GSZ - 1));
        int ix0 = (int)ix0f, iy0 = (int)iy0f;
        int ix1 = min(ix0 + 1, GSZ - 1);
        int iy1 = min(iy0 + 1, GSZ - 1);
        wx[i] = ix - ix0f;
        wy[i] = iy - iy0f;
        q[i][0] = iy0 * GSZ + ix0;
        q[i][1] = iy0 * GSZ + ix1;
        q[i][2] = iy1 * GSZ + ix0;
        q[i][3] = iy1 * GSZ + ix1;
        float iz = (gz[i] + 1.0f) * 0.5f * (float)(GSZ - 1);
        float iz0f = fminf(fmaxf(floorf(iz), 0.0f), (float)(GSZ - 1));
        int iz0 = (int)iz0f;
        int iz1 = min(iz0 + 1, GSZ - 1);
        wz[i] = iz - iz0f;
        lz[i][0] = iz0;
        lz[i][1] = iz1;
    }
    const size_t CN = (size_t)CCH * (size_t)N;
    for (int c = 0; c < CCH; ++c) {
        #pragma unroll
        for (int i = 0; i < 3; ++i) {
            const float* pp = (i == 0) ? p0 : (i == 1) ? p1 : p2;
            const float* ll = (i == 0) ? l0 : (i == 1) ? l1 : l2;
            const float* pc_ = pp + (size_t)c * GG;
            float v00 = pc_[q[i][0]];
            float v01 = pc_[q[i][1]];
            float v10 = pc_[q[i][2]];
            float v11 = pc_[q[i][3]];
            float top = fmaf(wx[i], v01 - v00, v00);
            float bot = fmaf(wx[i], v11 - v10, v10);
            float pcv = fmaf(wy[i], bot - top, top);
            float lv0 = ll[c * GSZ + lz[i][0]];
            float lv1 = ll[c * GSZ + lz[i][1]];
            float lc  = fmaf(wz[i], lv1 - lv0, lv0);
            out[(size_t)i * CN + (size_t)c * N + n] = pcv * lc;
        }
    }
}

extern "C" void kernel_launch(void* const* d_in, const int* in_sizes, int n_in,
                              void* d_out, int out_size, void* d_ws, size_t ws_size,
                              hipStream_t stream) {
    const float* xyz = (const float*)d_in[0];
    const float* pl0 = (const float*)d_in[1];
    const float* pl1 = (const float*)d_in[2];
    const float* pl2 = (const float*)d_in[3];
    const float* ln0 = (const float*)d_in[4];
    const float* ln1 = (const float*)d_in[5];
    const float* ln2 = (const float*)d_in[6];
    float* out = (float*)d_out;
    const int N = in_sizes[0] / 3;

    const size_t planeElems = (size_t)GG * CCH;     // 12,582,912
    const size_t lineElems  = (size_t)GSZ * CCH;    // 24,576
    const size_t need = (3 * planeElems + 3 * lineElems) * sizeof(__half); // ~75.6 MB

    if (ws_size >= need) {
        __half* wp0 = (__half*)d_ws;
        __half* wp1 = wp0 + planeElems;
        __half* wp2 = wp1 + planeElems;
        __half* wl0 = wp2 + planeElems;
        __half* wl1 = wl0 + lineElems;
        __half* wl2 = wl1 + lineElems;

        transpose_plane<<<GG / 64, 256, 0, stream>>>(pl0, wp0);
        transpose_plane<<<GG / 64, 256, 0, stream>>>(pl1, wp1);
        transpose_plane<<<GG / 64, 256, 0, stream>>>(pl2, wp2);
        transpose_lines<<<(3 * CCH * GSZ + 255) / 256, 256, 0, stream>>>(
            ln0, ln1, ln2, wl0, wl1, wl2);
        gather_fused<<<(N + 255) / 256, 256, 0, stream>>>(
            xyz, wp0, wp1, wp2, wl0, wl1, wl2, out, N);
    } else {
        gather_direct<<<(N + 255) / 256, 256, 0, stream>>>(
            xyz, pl0, pl1, pl2, ln0, ln1, ln2, out, N);
    }
}

// Round 2
// 885.101 us; speedup vs baseline: 1.0632x; 1.0632x over previous
//
#include <hip/hip_runtime.h>
#include <hip/hip_fp16.h>

#define GSZ 512
#define CCH 48
#define GG (GSZ*GSZ)
#define CBITS 5
#define CDIM (1 << CBITS)          // 32 cells per axis
#define CELLS (CDIM * CDIM * CDIM) // 32768

// ---------------- repack planes [C,H,W] fp32 -> [H*W, C] fp16 (all 3 in one launch) ----------------
__global__ __launch_bounds__(256) void transpose_planes3(
    const float* __restrict__ i0, const float* __restrict__ i1, const float* __restrict__ i2,
    __half* __restrict__ o0, __half* __restrict__ o1, __half* __restrict__ o2) {
    const float* in = (blockIdx.y == 0) ? i0 : (blockIdx.y == 1) ? i1 : i2;
    __half* out     = (blockIdx.y == 0) ? o0 : (blockIdx.y == 1) ? o1 : o2;
    __shared__ float tile[CCH][65];
    const int t = threadIdx.x;
    const int pos0 = blockIdx.x * 64;
    #pragma unroll
    for (int k = 0; k < 12; ++k) {
        int e = k * 256 + t;
        int c = e >> 6;
        int p = e & 63;
        tile[c][p] = in[c * GG + pos0 + p];
    }
    __syncthreads();
    #pragma unroll
    for (int k = 0; k < 6; ++k) {
        int e = (k * 256 + t) * 2;
        int p = e / 48;
        int c = e - p * 48;
        __half2 h;
        h.x = __float2half(tile[c][p]);
        h.y = __float2half(tile[c + 1][p]);
        *((__half2*)(out + (size_t)pos0 * CCH + e)) = h;
    }
}

// ---------------- repack lines [C,G] fp32 -> [G, C] fp16 ----------------
__global__ __launch_bounds__(256) void transpose_lines(
    const float* __restrict__ i0, const float* __restrict__ i1, const float* __restrict__ i2,
    __half* __restrict__ o0, __half* __restrict__ o1, __half* __restrict__ o2) {
    int idx = blockIdx.x * blockDim.x + threadIdx.x;
    const int total = CCH * GSZ;
    if (idx >= 3 * total) return;
    int w = idx / total;
    int r = idx - w * total;
    int c = r / GSZ;
    int p = r - c * GSZ;
    const float* in = (w == 0) ? i0 : (w == 1) ? i1 : i2;
    __half* out = (w == 0) ? o0 : (w == 1) ? o1 : o2;
    out[p * CCH + c] = __float2half(in[c * GSZ + p]);
}

// ---------------- Morton cell id ----------------
__device__ __forceinline__ unsigned spread5(unsigned a) {
    a &= 31u;
    a = (a | (a << 8)) & 0x100Fu;
    a = (a | (a << 4)) & 0x10C3u;
    a = (a | (a << 2)) & 0x1249u;
    return a;
}
__device__ __forceinline__ unsigned cell_of(float x, float y, float z) {
    const float s = 0.5f * (float)CDIM;
    unsigned cx = (unsigned)fminf(fmaxf((x + 1.0f) * s, 0.0f), (float)(CDIM - 1));
    unsigned cy = (unsigned)fminf(fmaxf((y + 1.0f) * s, 0.0f), (float)(CDIM - 1));
    unsigned cz = (unsigned)fminf(fmaxf((z + 1.0f) * s, 0.0f), (float)(CDIM - 1));
    return spread5(cx) | (spread5(cy) << 1) | (spread5(cz) << 2);
}

__global__ __launch_bounds__(256) void hist_k(const float* __restrict__ xyz,
                                              unsigned* __restrict__ hist, int N) {
    int n = blockIdx.x * 256 + threadIdx.x;
    if (n >= N) return;
    float x = xyz[3 * n], y = xyz[3 * n + 1], z = xyz[3 * n + 2];
    atomicAdd(&hist[cell_of(x, y, z)], 1u);
}

// single-block exclusive scan over CELLS bins (1024 threads x 32 bins)
__global__ __launch_bounds__(1024) void scan_k(unsigned* __restrict__ h) {
    __shared__ unsigned partials[1024];
    const int t = threadIdx.x;
    unsigned loc[CELLS / 1024];
    unsigned s = 0;
    #pragma unroll
    for (int j = 0; j < CELLS / 1024; ++j) { loc[j] = h[t * (CELLS / 1024) + j]; s += loc[j]; }
    partials[t] = s;
    __syncthreads();
    for (int off = 1; off < 1024; off <<= 1) {
        unsigned v = (t >= off) ? partials[t - off] : 0u;
        __syncthreads();
        partials[t] += v;
        __syncthreads();
    }
    unsigned running = (t > 0) ? partials[t - 1] : 0u;
    #pragma unroll
    for (int j = 0; j < CELLS / 1024; ++j) {
        unsigned c = loc[j];
        h[t * (CELLS / 1024) + j] = running;
        running += c;
    }
}

__global__ __launch_bounds__(256) void scatter_k(const float* __restrict__ xyz,
                                                 unsigned* __restrict__ offs,
                                                 unsigned* __restrict__ invPerm,
                                                 float4* __restrict__ sxyz, int N) {
    int n = blockIdx.x * 256 + threadIdx.x;
    if (n >= N) return;
    float x = xyz[3 * n], y = xyz[3 * n + 1], z = xyz[3 * n + 2];
    unsigned p = atomicAdd(&offs[cell_of(x, y, z)], 1u);
    invPerm[n] = p;
    sxyz[p] = make_float4(x, y, z, 0.0f);
}

union H8 { int4 v; __half h[8]; };

// ---------------- gather in sorted order -> fp16 feats [p][144] ----------------
__global__ __launch_bounds__(256) void gather_sorted(
    const float4* __restrict__ sxyz,
    const __half* __restrict__ p0, const __half* __restrict__ p1, const __half* __restrict__ p2,
    const __half* __restrict__ l0, const __half* __restrict__ l1, const __half* __restrict__ l2,
    __half* __restrict__ feats, int N) {
    int b = blockIdx.x, nb = gridDim.x;
    int chunk = ((nb & 7) == 0) ? ((b & 7) * (nb >> 3) + (b >> 3)) : b;  // XCD-contiguous Morton segments
    int p = chunk * 256 + threadIdx.x;
    if (p >= N) return;
    float4 q = sxyz[p];
    float x = q.x, y = q.y, z = q.z;

    float gx[3] = {x, x, y};
    float gy[3] = {y, z, z};
    float gz[3] = {z, y, x};
    int po[3][4], lo[3][2];
    float wx[3], wy[3], wz[3];
    #pragma unroll
    for (int i = 0; i < 3; ++i) {
        float ix = (gx[i] + 1.0f) * 0.5f * (float)(GSZ - 1);
        float iy = (gy[i] + 1.0f) * 0.5f * (float)(GSZ - 1);
        float ix0f = fminf(fmaxf(floorf(ix), 0.0f), (float)(GSZ - 1));
        float iy0f = fminf(fmaxf(floorf(iy), 0.0f), (float)(GSZ - 1));
        int ix0 = (int)ix0f, iy0 = (int)iy0f;
        int ix1 = min(ix0 + 1, GSZ - 1);
        int iy1 = min(iy0 + 1, GSZ - 1);
        wx[i] = ix - ix0f;
        wy[i] = iy - iy0f;
        po[i][0] = (iy0 * GSZ + ix0) * CCH;
        po[i][1] = (iy0 * GSZ + ix1) * CCH;
        po[i][2] = (iy1 * GSZ + ix0) * CCH;
        po[i][3] = (iy1 * GSZ + ix1) * CCH;
        float iz = (gz[i] + 1.0f) * 0.5f * (float)(GSZ - 1);
        float iz0f = fminf(fmaxf(floorf(iz), 0.0f), (float)(GSZ - 1));
        int iz0 = (int)iz0f;
        int iz1 = min(iz0 + 1, GSZ - 1);
        wz[i] = iz - iz0f;
        lo[i][0] = iz0 * CCH;
        lo[i][1] = iz1 * CCH;
    }

    __half* fb = feats + (size_t)p * 144;
    #pragma unroll
    for (int i = 0; i < 3; ++i) {
        const __half* pp = (i == 0) ? p0 : (i == 1) ? p1 : p2;
        const __half* ll = (i == 0) ? l0 : (i == 1) ? l1 : l2;
        #pragma unroll
        for (int cc = 0; cc < CCH; cc += 8) {
            H8 a00, a01, a10, a11, b0, b1, r;
            a00.v = *(const int4*)(pp + po[i][0] + cc);
            a01.v = *(const int4*)(pp + po[i][1] + cc);
            a10.v = *(const int4*)(pp + po[i][2] + cc);
            a11.v = *(const int4*)(pp + po[i][3] + cc);
            b0.v  = *(const int4*)(ll + lo[i][0] + cc);
            b1.v  = *(const int4*)(ll + lo[i][1] + cc);
            #pragma unroll
            for (int j = 0; j < 8; ++j) {
                float v00 = __half2float(a00.h[j]);
                float v01 = __half2float(a01.h[j]);
                float v10 = __half2float(a10.h[j]);
                float v11 = __half2float(a11.h[j]);
                float top = fmaf(wx[i], v01 - v00, v00);
                float bot = fmaf(wx[i], v11 - v10, v10);
                float pc  = fmaf(wy[i], bot - top, top);
                float lv0 = __half2float(b0.h[j]);
                float lv1 = __half2float(b1.h[j]);
                float lc  = fmaf(wz[i], lv1 - lv0, lv0);
                r.h[j] = __float2half(pc * lc);
            }
            *(int4*)(fb + i * 48 + cc) = r.v;
        }
    }
}

// ---------------- permute: feats[p][144] fp16 -> out[i][c][n] fp32 ----------------
__global__ __launch_bounds__(256) void permute_k(
    const unsigned* __restrict__ invPerm, const __half* __restrict__ feats,
    float* __restrict__ out, int N) {
    int n = blockIdx.x * 256 + threadIdx.x;
    if (n >= N) return;
    const __half* fb = feats + (size_t)invPerm[n] * 144;
    const size_t CN = (size_t)CCH * (size_t)N;
    #pragma unroll
    for (int i = 0; i < 3; ++i) {
        H8 v[6];
        #pragma unroll
        for (int k = 0; k < 6; ++k) v[k].v = *(const int4*)(fb + i * 48 + k * 8);
        float* op = out + (size_t)i * CN + n;
        #pragma unroll
        for (int k = 0; k < 6; ++k)
            #pragma unroll
            for (int j = 0; j < 8; ++j)
                op[(size_t)(k * 8 + j) * N] = __half2float(v[k].h[j]);
    }
}

// ---------------- fused gather (fallback, writes out directly) ----------------
__global__ __launch_bounds__(256) void gather_fused(
    const float* __restrict__ xyz,
    const __half* __restrict__ p0, const __half* __restrict__ p1, const __half* __restrict__ p2,
    const __half* __restrict__ l0, const __half* __restrict__ l1, const __half* __restrict__ l2,
    float* __restrict__ out, int N) {
    int n = blockIdx.x * 256 + threadIdx.x;
    if (n >= N) return;
    float x = xyz[3 * n], y = xyz[3 * n + 1], z = xyz[3 * n + 2];
    float gx[3] = {x, x, y};
    float gy[3] = {y, z, z};
    float gz[3] = {z, y, x};
    int po[3][4], lo[3][2];
    float wx[3], wy[3], wz[3];
    #pragma unroll
    for (int i = 0; i < 3; ++i) {
        float ix = (gx[i] + 1.0f) * 0.5f * (float)(GSZ - 1);
        float iy = (gy[i] + 1.0f) * 0.5f * (float)(GSZ - 1);
        float ix0f = fminf(fmaxf(floorf(ix), 0.0f), (float)(GSZ - 1));
        float iy0f = fminf(fmaxf(floorf(iy), 0.0f), (float)(GSZ - 1));
        int ix0 = (int)ix0f, iy0 = (int)iy0f;
        int ix1 = min(ix0 + 1, GSZ - 1);
        int iy1 = min(iy0 + 1, GSZ - 1);
        wx[i] = ix - ix0f;
        wy[i] = iy - iy0f;
        po[i][0] = (iy0 * GSZ + ix0) * CCH;
        po[i][1] = (iy0 * GSZ + ix1) * CCH;
        po[i][2] = (iy1 * GSZ + ix0) * CCH;
        po[i][3] = (iy1 * GSZ + ix1) * CCH;
        float iz = (gz[i] + 1.0f) * 0.5f * (float)(GSZ - 1);
        float iz0f = fminf(fmaxf(floorf(iz), 0.0f), (float)(GSZ - 1));
        int iz0 = (int)iz0f;
        int iz1 = min(iz0 + 1, GSZ - 1);
        wz[i] = iz - iz0f;
        lo[i][0] = iz0 * CCH;
        lo[i][1] = iz1 * CCH;
    }
    const size_t CN = (size_t)CCH * (size_t)N;
    #pragma unroll
    for (int i = 0; i < 3; ++i) {
        const __half* pp = (i == 0) ? p0 : (i == 1) ? p1 : p2;
        const __half* ll = (i == 0) ? l0 : (i == 1) ? l1 : l2;
        float* op = out + (size_t)i * CN + n;
        #pragma unroll
        for (int cc = 0; cc < CCH; cc += 8) {
            H8 a00, a01, a10, a11, b0, b1;
            a00.v = *(const int4*)(pp + po[i][0] + cc);
            a01.v = *(const int4*)(pp + po[i][1] + cc);
            a10.v = *(const int4*)(pp + po[i][2] + cc);
            a11.v = *(const int4*)(pp + po[i][3] + cc);
            b0.v  = *(const int4*)(ll + lo[i][0] + cc);
            b1.v  = *(const int4*)(ll + lo[i][1] + cc);
            #pragma unroll
            for (int j = 0; j < 8; ++j) {
                float v00 = __half2float(a00.h[j]);
                float v01 = __half2float(a01.h[j]);
                float v10 = __half2float(a10.h[j]);
                float v11 = __half2float(a11.h[j]);
                float top = fmaf(wx[i], v01 - v00, v00);
                float bot = fmaf(wx[i], v11 - v10, v10);
                float pc  = fmaf(wy[i], bot - top, top);
                float lv0 = __half2float(b0.h[j]);
                float lv1 = __half2float(b1.h[j]);
                float lc  = fmaf(wz[i], lv1 - lv0, lv0);
                op[(size_t)(cc + j) * N] = pc * lc;
            }
        }
    }
}

// ---------------- deep fallback: direct fp32 gather ----------------
__global__ __launch_bounds__(256) void gather_direct(
    const float* __restrict__ xyz,
    const float* __restrict__ p0, const float* __restrict__ p1, const float* __restrict__ p2,
    const float* __restrict__ l0, const float* __restrict__ l1, const float* __restrict__ l2,
    float* __restrict__ out, int N) {
    int n = blockIdx.x * 256 + threadIdx.x;
    if (n >= N) return;
    float x = xyz[3 * n], y = xyz[3 * n + 1], z = xyz[3 * n + 2];
    float gx[3] = {x, x, y};
    float gy[3] = {y, z, z};
    float gz[3] = {z, y, x};
    int q[3][4], lz[3][2];
    float wx[3], wy[3], wz[3];
    #pragma unroll
    for (int i = 0; i < 3; ++i) {
        float ix = (gx[i] + 1.0f) * 0.5f * (float)(GSZ - 1);
        float iy = (gy[i] + 1.0f) * 0.5f * (float)(GSZ - 1);
        float ix0f = fminf(fmaxf(floorf(ix), 0.0f), (float)(GSZ - 1));
        float iy0f = fminf(fmaxf(floorf(iy), 0.0f), (float)(GSZ - 1));
        int ix0 = (int)ix0f, iy0 = (int)iy0f;
        int ix1 = min(ix0 + 1, GSZ - 1);
        int iy1 = min(iy0 + 1, GSZ - 1);
        wx[i] = ix - ix0f;
        wy[i] = iy - iy0f;
        q[i][0] = iy0 * GSZ + ix0;
        q[i][1] = iy0 * GSZ + ix1;
        q[i][2] = iy1 * GSZ + ix0;
        q[i][3] = iy1 * GSZ + ix1;
        float iz = (gz[i] + 1.0f) * 0.5f * (float)(GSZ - 1);
        float iz0f = fminf(fmaxf(floorf(iz), 0.0f), (float)(GSZ - 1));
        int iz0 = (int)iz0f;
        int iz1 = min(iz0 + 1, GSZ - 1);
        wz[i] = iz - iz0f;
        lz[i][0] = iz0;
        lz[i][1] = iz1;
    }
    const size_t CN = (size_t)CCH * (size_t)N;
    for (int c = 0; c < CCH; ++c) {
        #pragma unroll
        for (int i = 0; i < 3; ++i) {
            const float* pp = (i == 0) ? p0 : (i == 1) ? p1 : p2;
            const float* ll = (i == 0) ? l0 : (i == 1) ? l1 : l2;
            const float* pc_ = pp + (size_t)c * GG;
            float v00 = pc_[q[i][0]];
            float v01 = pc_[q[i][1]];
            float v10 = pc_[q[i][2]];
            float v11 = pc_[q[i][3]];
            float top = fmaf(wx[i], v01 - v00, v00);
            float bot = fmaf(wx[i], v11 - v10, v10);
            float pcv = fmaf(wy[i], bot - top, top);
            float lv0 = ll[c * GSZ + lz[i][0]];
            float lv1 = ll[c * GSZ + lz[i][1]];
            float lc  = fmaf(wz[i], lv1 - lv0, lv0);
            out[(size_t)i * CN + (size_t)c * N + n] = pcv * lc;
        }
    }
}

extern "C" void kernel_launch(void* const* d_in, const int* in_sizes, int n_in,
                              void* d_out, int out_size, void* d_ws, size_t ws_size,
                              hipStream_t stream) {
    const float* xyz = (const float*)d_in[0];
    const float* pl0 = (const float*)d_in[1];
    const float* pl1 = (const float*)d_in[2];
    const float* pl2 = (const float*)d_in[3];
    const float* ln0 = (const float*)d_in[4];
    const float* ln1 = (const float*)d_in[5];
    const float* ln2 = (const float*)d_in[6];
    float* out = (float*)d_out;
    const int N = in_sizes[0] / 3;

    const size_t planeElems = (size_t)GG * CCH;
    const size_t lineElems  = (size_t)GSZ * CCH;

    auto align256 = [](size_t v) { return (v + 255) & ~(size_t)255; };
    size_t off = 0;
    size_t o_planes = off; off = align256(off + 3 * planeElems * sizeof(__half));
    size_t o_lines  = off; off = align256(off + 3 * lineElems * sizeof(__half));
    size_t o_hist   = off; off = align256(off + (size_t)CELLS * sizeof(unsigned));
    size_t o_iperm  = off; off = align256(off + (size_t)N * sizeof(unsigned));
    size_t o_sxyz   = off; off = align256(off + (size_t)N * sizeof(float4));
    size_t o_feats  = off; off = align256(off + (size_t)N * 144 * sizeof(__half));
    const size_t need_sort = off;
    const size_t need_old  = align256(3 * planeElems * sizeof(__half)) +
                             align256(3 * lineElems * sizeof(__half));

    char* ws = (char*)d_ws;
    const int nblk = (N + 255) / 256;

    if (ws_size >= need_sort) {
        __half* wp0 = (__half*)(ws + o_planes);
        __half* wp1 = wp0 + planeElems;
        __half* wp2 = wp1 + planeElems;
        __half* wl0 = (__half*)(ws + o_lines);
        __half* wl1 = wl0 + lineElems;
        __half* wl2 = wl1 + lineElems;
        unsigned* hist  = (unsigned*)(ws + o_hist);
        unsigned* iperm = (unsigned*)(ws + o_iperm);
        float4*   sxyz  = (float4*)(ws + o_sxyz);
        __half*   feats = (__half*)(ws + o_feats);

        transpose_planes3<<<dim3(GG / 64, 3), 256, 0, stream>>>(pl0, pl1, pl2, wp0, wp1, wp2);
        transpose_lines<<<(3 * CCH * GSZ + 255) / 256, 256, 0, stream>>>(ln0, ln1, ln2, wl0, wl1, wl2);
        hipMemsetAsync(hist, 0, (size_t)CELLS * sizeof(unsigned), stream);
        hist_k<<<nblk, 256, 0, stream>>>(xyz, hist, N);
        scan_k<<<1, 1024, 0, stream>>>(hist);
        scatter_k<<<nblk, 256, 0, stream>>>(xyz, hist, iperm, sxyz, N);
        gather_sorted<<<nblk, 256, 0, stream>>>(sxyz, wp0, wp1, wp2, wl0, wl1, wl2, feats, N);
        permute_k<<<nblk, 256, 0, stream>>>(iperm, feats, out, N);
    } else if (ws_size >= need_old) {
        __half* wp0 = (__half*)(ws + o_planes);
        __half* wp1 = wp0 + planeElems;
        __half* wp2 = wp1 + planeElems;
        __half* wl0 = (__half*)(ws + o_lines);
        __half* wl1 = wl0 + lineElems;
        __half* wl2 = wl1 + lineElems;
        transpose_planes3<<<dim3(GG / 64, 3), 256, 0, stream>>>(pl0, pl1, pl2, wp0, wp1, wp2);
        transpose_lines<<<(3 * CCH * GSZ + 255) / 256, 256, 0, stream>>>(ln0, ln1, ln2, wl0, wl1, wl2);
        gather_fused<<<nblk, 256, 0, stream>>>(xyz, wp0, wp1, wp2, wl0, wl1, wl2, out, N);
    } else {
        gather_direct<<<nblk, 256, 0, stream>>>(xyz, pl0, pl1, pl2, ln0, ln1, ln2, out, N);
    }
}